// Round 2
// baseline (428.774 us; speedup 1.0000x reference)
//
#include <hip/hip_runtime.h>
#include <stdint.h>

// AQT int8 MLP block: M=8192 (=4*2048), C=1024, H=4096. All I/O float32.
// fake_quant values are q/s with integer q in [-127,127], so
// xq@wq == (qx_int @ qw_int) * (1/sx) * (1/sw[col])  -- exact in int32.

#define EPSQ 1e-6f
typedef int v4i __attribute__((ext_vector_type(4)));

__device__ __forceinline__ int8_t quant1(float x, float s) {
  return (int8_t)(int)fminf(fmaxf(rintf(x * s), -127.f), 127.f);
}
__device__ __forceinline__ void async16(const int8_t* g, int8_t* l) {
  __builtin_amdgcn_global_load_lds(
      (const __attribute__((address_space(1))) void*)g,
      (__attribute__((address_space(3))) void*)l, 16, 0, 0);
}

// ---- masked per-tensor absmax of x [8192,1024] f32, mask [8192] f32 ----
__global__ void k_absmax_x(const float* __restrict__ x,
                           const float* __restrict__ mask,
                           float* __restrict__ out) {
  __shared__ float red[4];
  const int tid = threadIdx.x;
  float lmax = 0.f;
  for (int c = blockIdx.x * 256 + tid; c < 1048576; c += 1024 * 256) {
    size_t idx = (size_t)c * 8;               // 8 floats per iter
    float mk = fabsf(mask[idx >> 10]);
    float4 a = *(const float4*)(x + idx);
    float4 b = *(const float4*)(x + idx + 4);
    float m = fmaxf(fmaxf(fmaxf(fabsf(a.x), fabsf(a.y)), fmaxf(fabsf(a.z), fabsf(a.w))),
                    fmaxf(fmaxf(fabsf(b.x), fabsf(b.y)), fmaxf(fabsf(b.z), fabsf(b.w))));
    lmax = fmaxf(lmax, m * mk);
  }
  for (int s = 32; s; s >>= 1) lmax = fmaxf(lmax, __shfl_down(lmax, s));
  if ((tid & 63) == 0) red[tid >> 6] = lmax;
  __syncthreads();
  if (tid == 0)
    atomicMax((unsigned int*)out,
              __float_as_uint(fmaxf(fmaxf(red[0], red[1]), fmaxf(red[2], red[3]))));
}

// ---- per-column absmax of W [K,N] f32 ----
__global__ void k_colmax(const float* __restrict__ W,
                         float* __restrict__ cmax, int N, int rowsPerBlk) {
  int col = blockIdx.x * 256 + threadIdx.x;
  int r0 = blockIdx.y * rowsPerBlk;
  float m = 0.f;
  for (int r = 0; r < rowsPerBlk; ++r)
    m = fmaxf(m, fabsf(W[(size_t)(r0 + r) * N + col]));
  atomicMax((unsigned int*)(cmax + col), __float_as_uint(m));
}

// ---- quantize x (f32) -> int8, 16 elems/thread ----
__global__ void k_quant_x(const float* __restrict__ x,
                          const float* __restrict__ sc, int8_t* __restrict__ q) {
  const float s = 127.0f / fmaxf(sc[0], EPSQ);
  size_t idx = ((size_t)blockIdx.x * 256 + threadIdx.x) * 16;
  union { int8_t p[16]; uint4 v; } u;
#pragma unroll
  for (int i = 0; i < 16; i += 4) {
    float4 v = *(const float4*)(x + idx + i);
    u.p[i]     = quant1(v.x, s);
    u.p[i + 1] = quant1(v.y, s);
    u.p[i + 2] = quant1(v.z, s);
    u.p[i + 3] = quant1(v.w, s);
  }
  *(uint4*)(q + idx) = u.v;
}

// ---- quantize + transpose W [K,N] f32 -> qWt [N,K] int8 ----
__global__ void k_quant_wt(const float* __restrict__ W,
                           const float* __restrict__ cmax,
                           int8_t* __restrict__ out, int K, int N) {
  int id = blockIdx.x * 256 + threadIdx.x;   // N*K/16 total threads
  int n = id & (N - 1);
  int kc = id / N;
  const float s = 127.0f / fmaxf(cmax[n], EPSQ);
  union { int8_t p[16]; uint4 v; } u;
#pragma unroll
  for (int j = 0; j < 16; ++j)
    u.p[j] = quant1(W[(size_t)(kc * 16 + j) * N + n], s);
  *(uint4*)(out + (size_t)n * K + (size_t)kc * 16) = u.v;
}

// ---- quantize h (f32) -> int8 ----
__global__ void k_quant_h(const float* __restrict__ h,
                          const float* __restrict__ sc, int8_t* __restrict__ q) {
  const float s = 127.0f / fmaxf(sc[1], EPSQ);
  size_t idx = ((size_t)blockIdx.x * 256 + threadIdx.x) * 16;
  union { int8_t p[16]; uint4 v; } u;
#pragma unroll
  for (int i = 0; i < 16; i += 4) {
    float4 v = *(const float4*)(h + idx + i);
    u.p[i]     = quant1(v.x, s);
    u.p[i + 1] = quant1(v.y, s);
    u.p[i + 2] = quant1(v.z, s);
    u.p[i + 3] = quant1(v.w, s);
  }
  *(uint4*)(q + idx) = u.v;
}

// ---- int8 GEMM, A [M,K], Bt [N,K], 128x128 tile, BK=64, 4 waves (2x2 of 64x64)
// MODE 0: out f32 = relu(deq + bias), track masked hmax.  MODE 1: out f32 = deq + bias.
template <int MODE>
__global__ __launch_bounds__(256) void gemm_i8(
    const int8_t* __restrict__ A, const int8_t* __restrict__ Bt,
    const float* __restrict__ sc, const float* __restrict__ colmax,
    const float* __restrict__ bias, const float* __restrict__ mask,
    float* __restrict__ outF, float* __restrict__ hmax, int M, int N, int K) {
  __shared__ __align__(16) int8_t lsA[128 * 64];
  __shared__ __align__(16) int8_t lsB[128 * 64];
  __shared__ float red[4];
  const int tid = threadIdx.x;
  const int wave = tid >> 6, lane = tid & 63;
  const int m0 = blockIdx.y * 128, n0 = blockIdx.x * 128;
  const int wm = (wave & 1) * 64, wn = (wave >> 1) * 64;

  v4i acc[4][4] = {};

  const int srow = tid >> 2;
  const int skc = (tid & 3) * 16;
  const int8_t* gA = A + (size_t)(m0 + srow) * K + skc;
  const int8_t* gB = Bt + (size_t)(n0 + srow) * K + skc;
  const size_t rowstep = (size_t)64 * K;

  const int kq = (lane >> 4) * 16;
  const int rA = (wm + (lane & 15)) * 64 + kq;
  const int rB = (wn + (lane & 15)) * 64 + kq;

  for (int kb = 0; kb < K; kb += 64) {
    async16(gA, lsA + tid * 16);
    async16(gA + rowstep, lsA + 4096 + tid * 16);
    async16(gB, lsB + tid * 16);
    async16(gB + rowstep, lsB + 4096 + tid * 16);
    gA += 64; gB += 64;
    __syncthreads();
    v4i af[4], bf[4];
#pragma unroll
    for (int t = 0; t < 4; ++t) {
      af[t] = *(const v4i*)(lsA + rA + t * (16 * 64));
      bf[t] = *(const v4i*)(lsB + rB + t * (16 * 64));
    }
#pragma unroll
    for (int mt = 0; mt < 4; ++mt)
#pragma unroll
      for (int nt = 0; nt < 4; ++nt)
        acc[mt][nt] = __builtin_amdgcn_mfma_i32_16x16x64_i8(af[mt], bf[nt], acc[mt][nt], 0, 0, 0);
    __syncthreads();
  }

  const float asc = fmaxf(sc[MODE == 0 ? 0 : 1], EPSQ) * (1.0f / 127.0f);
  const int cl = lane & 15;
  const int rl = (lane >> 4) * 4;

  float bsc[4], bv[4];
#pragma unroll
  for (int nt = 0; nt < 4; ++nt) {
    int col = n0 + wn + nt * 16 + cl;
    bsc[nt] = fmaxf(colmax[col], EPSQ) * (1.0f / 127.0f) * asc;
    bv[nt] = bias[col];
  }

  if (MODE == 0) {
    float lmax = 0.f;
#pragma unroll
    for (int mt = 0; mt < 4; ++mt)
#pragma unroll
      for (int r = 0; r < 4; ++r) {
        int row = m0 + wm + mt * 16 + rl + r;
        float mk = fabsf(mask[row]);
        float* orow = outF + (size_t)row * N + n0 + wn + cl;
#pragma unroll
        for (int nt = 0; nt < 4; ++nt) {
          float v = (float)acc[mt][nt][r] * bsc[nt] + bv[nt];
          v = fmaxf(v, 0.f);
          orow[nt * 16] = v;
          lmax = fmaxf(lmax, v * mk);
        }
      }
    for (int s = 32; s; s >>= 1) lmax = fmaxf(lmax, __shfl_down(lmax, s));
    if (lane == 0) red[wave] = lmax;
    __syncthreads();
    if (tid == 0)
      atomicMax((unsigned int*)hmax,
                __float_as_uint(fmaxf(fmaxf(red[0], red[1]), fmaxf(red[2], red[3]))));
  } else {
#pragma unroll
    for (int mt = 0; mt < 4; ++mt)
#pragma unroll
      for (int r = 0; r < 4; ++r) {
        int row = m0 + wm + mt * 16 + rl + r;
        float* orow = outF + (size_t)row * N + n0 + wn + cl;
#pragma unroll
        for (int nt = 0; nt < 4; ++nt)
          orow[nt * 16] = (float)acc[mt][nt][r] * bsc[nt] + bv[nt];
      }
  }
}

extern "C" void kernel_launch(void* const* d_in, const int* in_sizes, int n_in,
                              void* d_out, int out_size, void* d_ws, size_t ws_size,
                              hipStream_t stream) {
  const float* x  = (const float*)d_in[0];  // [8192,1024]
  const float* mk = (const float*)d_in[1];  // [8192]
  const float* W1 = (const float*)d_in[2];  // [1024,4096]
  const float* b1 = (const float*)d_in[3];  // [4096]
  const float* W2 = (const float*)d_in[4];  // [4096,1024]
  const float* b2 = (const float*)d_in[5];  // [1024]
  float* out = (float*)d_out;               // [8192,1024]

  float* sc  = (float*)d_ws;        // sc[0]=x_absmax, sc[1]=h_absmax
  float* cm1 = sc + 8;              // [4096] col-absmax W1
  float* cm2 = cm1 + 4096;          // [1024] col-absmax W2
  int8_t* qx  = (int8_t*)(cm2 + 1024);        // 8 MiB
  int8_t* qw1 = qx  + (size_t)8192 * 1024;    // 4 MiB  [N=4096][K=1024]
  int8_t* qw2 = qw1 + (size_t)4096 * 1024;    // 4 MiB  [N=1024][K=4096]
  int8_t* qh  = qw2 + (size_t)1024 * 4096;    // 32 MiB
  float*  h   = (float*)(qh + (size_t)8192 * 4096);  // 128 MiB f32

  hipMemsetAsync(sc, 0, (8 + 4096 + 1024) * sizeof(float), stream);
  k_absmax_x<<<1024, 256, 0, stream>>>(x, mk, sc);
  k_colmax<<<dim3(16, 8), 256, 0, stream>>>(W1, cm1, 4096, 128);
  k_colmax<<<dim3(4, 32), 256, 0, stream>>>(W2, cm2, 1024, 128);
  k_quant_x<<<2048, 256, 0, stream>>>(x, sc, qx);
  k_quant_wt<<<1024, 256, 0, stream>>>(W1, cm1, qw1, 1024, 4096);
  k_quant_wt<<<1024, 256, 0, stream>>>(W2, cm2, qw2, 4096, 1024);
  gemm_i8<0><<<dim3(32, 64), 256, 0, stream>>>(qx, qw1, sc, cm1, b1, mk,
                                               h, sc + 1, 8192, 4096, 1024);
  k_quant_h<<<8192, 256, 0, stream>>>(h, sc, qh);
  gemm_i8<1><<<dim3(8, 64), 256, 0, stream>>>(qh, qw2, sc, cm2, b2, mk,
                                              out, nullptr, 8192, 1024, 4096);
}

// Round 3
// 404.363 us; speedup vs baseline: 1.0604x; 1.0604x over previous
//
#include <hip/hip_runtime.h>
#include <hip/hip_fp16.h>
#include <stdint.h>

// AQT int8 MLP: M=8192, C=1024, H=4096. All I/O float32.
// Exact path: fake_quant values are q/s (integer q), so xq@wq is exact in int32 MFMA.
// 5 dispatches: stats -> quant(x,W1t,W2t) -> GEMM1(h fp16 + block hmax) -> quant_h -> GEMM2.

#define EPSQ 1e-6f
typedef int v4i __attribute__((ext_vector_type(4)));

__device__ __forceinline__ int8_t quant1(float x, float s) {
  return (int8_t)(int)fminf(fmaxf(rintf(x * s), -127.f), 127.f);
}
__device__ __forceinline__ void async16(const int8_t* g, int8_t* l) {
  __builtin_amdgcn_global_load_lds(
      (const __attribute__((address_space(1))) void*)g,
      (__attribute__((address_space(3))) void*)l, 16, 0, 0);
}
__device__ __forceinline__ unsigned short f2h(float f) {
  __half h = __float2half(f);
  return *(unsigned short*)&h;
}
__device__ __forceinline__ float h2f(unsigned short u) {
  __half h = *(__half*)&u;
  return __half2float(h);
}

// ================== dispatch 1: stats (W1/W2 partial colmax + masked x absmax) =====
__global__ __launch_bounds__(256) void k_stats(
    const float* __restrict__ x, const float* __restrict__ mask,
    const float* __restrict__ W1, const float* __restrict__ W2,
    float* __restrict__ pmaxX, float* __restrict__ pcm1, float* __restrict__ pcm2) {
  const int bx = blockIdx.x, tid = threadIdx.x;
  if (bx < 64) {                       // W1 [1024,4096]: 16 colblocks x 4 row-splits
    const int cb = bx >> 2, sp = bx & 3;
    const int col = cb * 256 + tid;
    float m = 0.f;
#pragma unroll 8
    for (int r = 0; r < 256; ++r)
      m = fmaxf(m, fabsf(W1[(size_t)(sp * 256 + r) * 4096 + col]));
    pcm1[sp * 4096 + col] = m;
  } else if (bx < 128) {               // W2 [4096,1024]: 4 colblocks x 16 row-splits
    const int b = bx - 64, cb = b >> 4, sp = b & 15;
    const int col = cb * 256 + tid;
    float m = 0.f;
#pragma unroll 8
    for (int r = 0; r < 256; ++r)
      m = fmaxf(m, fabsf(W2[(size_t)(sp * 256 + r) * 1024 + col]));
    pcm2[sp * 1024 + col] = m;
  } else {                             // masked absmax of x -> per-block partial
    __shared__ float red[4];
    const int b = bx - 128;            // 1024 blocks
    float lmax = 0.f;
    for (int c = b * 256 + tid; c < 1048576; c += 262144) {
      size_t idx = (size_t)c * 8;
      float mk = fabsf(mask[idx >> 10]);
      float4 a = *(const float4*)(x + idx);
      float4 bb = *(const float4*)(x + idx + 4);
      float m = fmaxf(fmaxf(fmaxf(fabsf(a.x), fabsf(a.y)), fmaxf(fabsf(a.z), fabsf(a.w))),
                      fmaxf(fmaxf(fabsf(bb.x), fabsf(bb.y)), fmaxf(fabsf(bb.z), fabsf(bb.w))));
      lmax = fmaxf(lmax, m * mk);
    }
    for (int s = 32; s; s >>= 1) lmax = fmaxf(lmax, __shfl_down(lmax, s));
    if ((tid & 63) == 0) red[tid >> 6] = lmax;
    __syncthreads();
    if (tid == 0)
      pmaxX[b] = fmaxf(fmaxf(red[0], red[1]), fmaxf(red[2], red[3]));
  }
}

// ================== dispatch 2: quantize x, W1->qW1t, W2->qW2t ======================
__global__ __launch_bounds__(256) void k_quant(
    const float* __restrict__ x, const float* __restrict__ W1, const float* __restrict__ W2,
    const float* __restrict__ pmaxX, const float* __restrict__ pcm1, const float* __restrict__ pcm2,
    int8_t* __restrict__ qx, int8_t* __restrict__ qw1, int8_t* __restrict__ qw2,
    float* __restrict__ cm1, float* __restrict__ cm2, float* __restrict__ scG) {
  const int bx = blockIdx.x, tid = threadIdx.x;
  if (bx < 2048) {                     // x: reduce pmaxX then quantize 16 f32 -> int8
    __shared__ float red[4];
    float v = fmaxf(fmaxf(pmaxX[tid], pmaxX[tid + 256]),
                    fmaxf(pmaxX[tid + 512], pmaxX[tid + 768]));
    for (int s = 32; s; s >>= 1) v = fmaxf(v, __shfl_down(v, s));
    if ((tid & 63) == 0) red[tid >> 6] = v;
    __syncthreads();
    const float xmax = fmaxf(fmaxf(red[0], red[1]), fmaxf(red[2], red[3]));
    if (bx == 0 && tid == 0) scG[0] = xmax;
    const float s = 127.0f / fmaxf(xmax, EPSQ);
    size_t idx = ((size_t)bx * 256 + tid) * 16;
    union { int8_t p[16]; uint4 v; } u;
#pragma unroll
    for (int i = 0; i < 16; i += 4) {
      float4 f = *(const float4*)(x + idx + i);
      u.p[i] = quant1(f.x, s); u.p[i + 1] = quant1(f.y, s);
      u.p[i + 2] = quant1(f.z, s); u.p[i + 3] = quant1(f.w, s);
    }
    *(uint4*)(qx + idx) = u.v;
  } else if (bx < 3072) {              // W1 [1024,4096] -> qw1t [4096,1024]
    int id = (bx - 2048) * 256 + tid;
    int n = id & 4095, kc = id >> 12;
    float cmv = 0.f;
#pragma unroll
    for (int sp = 0; sp < 4; ++sp) cmv = fmaxf(cmv, pcm1[sp * 4096 + n]);
    if (kc == 0) cm1[n] = cmv;
    const float s = 127.0f / fmaxf(cmv, EPSQ);
    union { int8_t p[16]; uint4 v; } u;
#pragma unroll
    for (int j = 0; j < 16; ++j)
      u.p[j] = quant1(W1[(size_t)(kc * 16 + j) * 4096 + n], s);
    *(uint4*)(qw1 + (size_t)n * 1024 + kc * 16) = u.v;
  } else {                             // W2 [4096,1024] -> qw2t [1024,4096]
    int id = (bx - 3072) * 256 + tid;
    int n = id & 1023, kc = id >> 10;
    float cmv = 0.f;
#pragma unroll
    for (int sp = 0; sp < 16; ++sp) cmv = fmaxf(cmv, pcm2[sp * 1024 + n]);
    if (kc == 0) cm2[n] = cmv;
    const float s = 127.0f / fmaxf(cmv, EPSQ);
    union { int8_t p[16]; uint4 v; } u;
#pragma unroll
    for (int j = 0; j < 16; ++j)
      u.p[j] = quant1(W2[(size_t)(kc * 16 + j) * 1024 + n], s);
    *(uint4*)(qw2 + (size_t)n * 4096 + kc * 16) = u.v;
  }
}

// ================== GEMM: A [M,K] x Bt [N,K], block BM x BN, 4 waves 2x2 ============
// wave-tile (MT*16) x (NT*16). BK=64. XOR-swizzled LDS (2-way floor = free).
// MODE 0: h fp16 = relu(deq+bias), per-block masked max -> pmaxH.  MODE 1: f32 out.
template <int BM, int BN, int MT, int NT, int MODE>
__global__ __launch_bounds__(256) void gemm_i8(
    const int8_t* __restrict__ A, const int8_t* __restrict__ Bt,
    const float* __restrict__ sxp, const float* __restrict__ cmax,
    const float* __restrict__ bias, const float* __restrict__ mask,
    void* __restrict__ outp, float* __restrict__ pmaxH, int M, int N, int K) {
  constexpr int GA = BM / 64, GB = BN / 64;
  __shared__ __align__(16) int8_t lsA[BM * 64];
  __shared__ __align__(16) int8_t lsB[BN * 64];
  __shared__ float red[4];
  const int tid = threadIdx.x;
  const int wave = tid >> 6, lane = tid & 63;
  const int m0 = blockIdx.y * BM, n0 = blockIdx.x * BN;
  const int wm = (wave & 1) * (MT * 16), wn = (wave >> 1) * (NT * 16);

  v4i acc[MT][NT] = {};

  // staging: thread covers LDS row r=tid>>2, chunk c=tid&3; source chunk swizzled
  const int r = tid >> 2, c = tid & 3;
  const int8_t* srcA[GA];
  const int8_t* srcB[GB];
#pragma unroll
  for (int g = 0; g < GA; ++g) {
    int R = g * 64 + r;
    srcA[g] = A + (size_t)(m0 + R) * K + ((c ^ ((R >> 1) & 3)) << 4);
  }
#pragma unroll
  for (int g = 0; g < GB; ++g) {
    int R = g * 64 + r;
    srcB[g] = Bt + (size_t)(n0 + R) * K + ((c ^ ((R >> 1) & 3)) << 4);
  }

  // fragment read offsets (16x16x64: row = lane&15, k-chunk = lane>>4)
  const int fr = lane & 15, fj = lane >> 4;
  const int coff = ((fj ^ ((fr >> 1) & 3)) << 4);

  for (int kb = 0; kb < K; kb += 64) {
#pragma unroll
    for (int g = 0; g < GA; ++g) async16(srcA[g] + kb, lsA + g * 4096 + tid * 16);
#pragma unroll
    for (int g = 0; g < GB; ++g) async16(srcB[g] + kb, lsB + g * 4096 + tid * 16);
    __syncthreads();
    v4i af[MT], bf[NT];
#pragma unroll
    for (int mt = 0; mt < MT; ++mt)
      af[mt] = *(const v4i*)(lsA + (wm + mt * 16 + fr) * 64 + coff);
#pragma unroll
    for (int nt = 0; nt < NT; ++nt)
      bf[nt] = *(const v4i*)(lsB + (wn + nt * 16 + fr) * 64 + coff);
#pragma unroll
    for (int mt = 0; mt < MT; ++mt)
#pragma unroll
      for (int nt = 0; nt < NT; ++nt)
        acc[mt][nt] = __builtin_amdgcn_mfma_i32_16x16x64_i8(af[mt], bf[nt], acc[mt][nt], 0, 0, 0);
    __syncthreads();
  }

  const float asc = fmaxf(sxp[0], EPSQ) * (1.0f / 127.0f);
  const int cl = lane & 15;
  const int rl = (lane >> 4) * 4;

  float bsc[NT], bv[NT];
#pragma unroll
  for (int nt = 0; nt < NT; ++nt) {
    int col = n0 + wn + nt * 16 + cl;
    bsc[nt] = fmaxf(cmax[col], EPSQ) * (1.0f / 127.0f) * asc;
    bv[nt] = bias[col];
  }

  if (MODE == 0) {
    unsigned short* hO = (unsigned short*)outp;
    float lmax = 0.f;
#pragma unroll
    for (int mt = 0; mt < MT; ++mt)
#pragma unroll
      for (int rr = 0; rr < 4; ++rr) {
        int row = m0 + wm + mt * 16 + rl + rr;
        float mk = fabsf(mask[row]);
        unsigned short* orow = hO + (size_t)row * N + n0 + wn + cl;
#pragma unroll
        for (int nt = 0; nt < NT; ++nt) {
          float v = (float)acc[mt][nt][rr] * bsc[nt] + bv[nt];
          v = fmaxf(v, 0.f);
          orow[nt * 16] = f2h(v);
          lmax = fmaxf(lmax, v * mk);
        }
      }
    for (int s = 32; s; s >>= 1) lmax = fmaxf(lmax, __shfl_down(lmax, s));
    if (lane == 0) red[wave] = lmax;
    __syncthreads();
    if (tid == 0)
      pmaxH[blockIdx.y * gridDim.x + blockIdx.x] =
          fmaxf(fmaxf(red[0], red[1]), fmaxf(red[2], red[3]));
  } else {
    float* oO = (float*)outp;
#pragma unroll
    for (int mt = 0; mt < MT; ++mt)
#pragma unroll
      for (int rr = 0; rr < 4; ++rr) {
        int row = m0 + wm + mt * 16 + rl + rr;
        float* orow = oO + (size_t)row * N + n0 + wn + cl;
#pragma unroll
        for (int nt = 0; nt < NT; ++nt)
          orow[nt * 16] = (float)acc[mt][nt][rr] * bsc[nt] + bv[nt];
      }
  }
}

// ================== dispatch 4: quantize h (fp16) -> int8 ==========================
__global__ __launch_bounds__(256) void k_quant_h(
    const unsigned short* __restrict__ h, const float* __restrict__ pmaxH,
    float* __restrict__ scG, int8_t* __restrict__ q) {
  __shared__ float red[4];
  const int tid = threadIdx.x;
  float v = fmaxf(fmaxf(pmaxH[tid], pmaxH[tid + 256]),
                  fmaxf(pmaxH[tid + 512], pmaxH[tid + 768]));
  for (int s = 32; s; s >>= 1) v = fmaxf(v, __shfl_down(v, s));
  if ((tid & 63) == 0) red[tid >> 6] = v;
  __syncthreads();
  const float hmax = fmaxf(fmaxf(red[0], red[1]), fmaxf(red[2], red[3]));
  if (blockIdx.x == 0 && tid == 0) scG[1] = hmax;
  const float s = 127.0f / fmaxf(hmax, EPSQ);
  size_t idx = ((size_t)blockIdx.x * 256 + tid) * 16;
  union { uint4 v; unsigned short s[8]; } a, b;
  a.v = *(const uint4*)(h + idx);
  b.v = *(const uint4*)(h + idx + 8);
  union { int8_t p[16]; uint4 v; } u;
#pragma unroll
  for (int i = 0; i < 8; ++i) {
    u.p[i] = quant1(h2f(a.s[i]), s);
    u.p[i + 8] = quant1(h2f(b.s[i]), s);
  }
  *(uint4*)(q + idx) = u.v;
}

extern "C" void kernel_launch(void* const* d_in, const int* in_sizes, int n_in,
                              void* d_out, int out_size, void* d_ws, size_t ws_size,
                              hipStream_t stream) {
  const float* x  = (const float*)d_in[0];   // [8192,1024]
  const float* mk = (const float*)d_in[1];   // [8192]
  const float* W1 = (const float*)d_in[2];   // [1024,4096]
  const float* b1 = (const float*)d_in[3];   // [4096]
  const float* W2 = (const float*)d_in[4];   // [4096,1024]
  const float* b2 = (const float*)d_in[5];   // [1024]
  float* out = (float*)d_out;                // [8192,1024]

  float* scG   = (float*)d_ws;               // [8]
  float* pmaxX = scG + 8;                    // [1024]
  float* pmaxH = pmaxX + 1024;               // [1024]
  float* pcm1  = pmaxH + 1024;               // [4*4096]
  float* pcm2  = pcm1 + 16384;               // [16*1024]
  float* cm1   = pcm2 + 16384;               // [4096]
  float* cm2   = cm1 + 4096;                 // [1024]
  int8_t* qx  = (int8_t*)(cm2 + 1024);           // 8 MiB
  int8_t* qw1 = qx  + (size_t)8192 * 1024;       // 4 MiB  [4096][1024]
  int8_t* qw2 = qw1 + (size_t)4096 * 1024;       // 4 MiB  [1024][4096]
  int8_t* qh  = qw2 + (size_t)1024 * 4096;       // 32 MiB
  unsigned short* h = (unsigned short*)(qh + (size_t)8192 * 4096);  // 64 MiB fp16

  k_stats<<<1152, 256, 0, stream>>>(x, mk, W1, W2, pmaxX, pcm1, pcm2);
  k_quant<<<4096, 256, 0, stream>>>(x, W1, W2, pmaxX, pcm1, pcm2,
                                    qx, qw1, qw2, cm1, cm2, scG);
  gemm_i8<128, 256, 4, 8, 0><<<dim3(16, 64), 256, 0, stream>>>(
      qx, qw1, scG, cm1, b1, mk, (void*)h, pmaxH, 8192, 4096, 1024);
  k_quant_h<<<8192, 256, 0, stream>>>(h, pmaxH, scG, qh);
  gemm_i8<256, 128, 8, 4, 1><<<dim3(8, 32), 256, 0, stream>>>(
      qh, qw2, scG + 1, cm2, b2, mk, (void*)out, nullptr, 8192, 1024, 4096);
}

// Round 4
// 335.992 us; speedup vs baseline: 1.2761x; 1.2035x over previous
//
#include <hip/hip_runtime.h>
#include <hip/hip_fp16.h>
#include <stdint.h>

// AQT int8 MLP: M=8192, C=1024, H=4096. All I/O float32.
// Exact path: fake_quant values are q/s (integer q), so xq@wq is exact in int32 MFMA.
// 5 dispatches: stats -> quant(x,W1t,W2t) -> GEMM1(h fp16 + block hmax) -> quant_h -> GEMM2.
// GEMM: 128x128 block, 2x2 waves of 64x64, BK=64, LDS double-buffer, 1 barrier/step.

#define EPSQ 1e-6f
typedef int v4i __attribute__((ext_vector_type(4)));

__device__ __forceinline__ int8_t quant1(float x, float s) {
  return (int8_t)(int)fminf(fmaxf(rintf(x * s), -127.f), 127.f);
}
__device__ __forceinline__ void async16(const int8_t* g, int8_t* l) {
  __builtin_amdgcn_global_load_lds(
      (const __attribute__((address_space(1))) void*)g,
      (__attribute__((address_space(3))) void*)l, 16, 0, 0);
}
__device__ __forceinline__ unsigned short f2h(float f) {
  __half h = __float2half(f);
  return *(unsigned short*)&h;
}
__device__ __forceinline__ float h2f(unsigned short u) {
  __half h = *(__half*)&u;
  return __half2float(h);
}

// ================== dispatch 1: stats (W1/W2 partial colmax + masked x absmax) =====
__global__ __launch_bounds__(256) void k_stats(
    const float* __restrict__ x, const float* __restrict__ mask,
    const float* __restrict__ W1, const float* __restrict__ W2,
    float* __restrict__ pmaxX, float* __restrict__ pcm1, float* __restrict__ pcm2) {
  const int bx = blockIdx.x, tid = threadIdx.x;
  if (bx < 64) {                       // W1 [1024,4096]: 16 colblocks x 4 row-splits
    const int cb = bx >> 2, sp = bx & 3;
    const int col = cb * 256 + tid;
    float m = 0.f;
#pragma unroll 8
    for (int r = 0; r < 256; ++r)
      m = fmaxf(m, fabsf(W1[(size_t)(sp * 256 + r) * 4096 + col]));
    pcm1[sp * 4096 + col] = m;
  } else if (bx < 128) {               // W2 [4096,1024]: 4 colblocks x 16 row-splits
    const int b = bx - 64, cb = b >> 4, sp = b & 15;
    const int col = cb * 256 + tid;
    float m = 0.f;
#pragma unroll 8
    for (int r = 0; r < 256; ++r)
      m = fmaxf(m, fabsf(W2[(size_t)(sp * 256 + r) * 1024 + col]));
    pcm2[sp * 1024 + col] = m;
  } else {                             // masked absmax of x -> per-block partial
    __shared__ float red[4];
    const int b = bx - 128;            // 1024 blocks
    float lmax = 0.f;
    for (int c = b * 256 + tid; c < 1048576; c += 262144) {
      size_t idx = (size_t)c * 8;
      float mk = fabsf(mask[idx >> 10]);
      float4 a = *(const float4*)(x + idx);
      float4 bb = *(const float4*)(x + idx + 4);
      float m = fmaxf(fmaxf(fmaxf(fabsf(a.x), fabsf(a.y)), fmaxf(fabsf(a.z), fabsf(a.w))),
                      fmaxf(fmaxf(fabsf(bb.x), fabsf(bb.y)), fmaxf(fabsf(bb.z), fabsf(bb.w))));
      lmax = fmaxf(lmax, m * mk);
    }
    for (int s = 32; s; s >>= 1) lmax = fmaxf(lmax, __shfl_down(lmax, s));
    if ((tid & 63) == 0) red[tid >> 6] = lmax;
    __syncthreads();
    if (tid == 0)
      pmaxX[b] = fmaxf(fmaxf(red[0], red[1]), fmaxf(red[2], red[3]));
  }
}

// ================== dispatch 2: quantize x, W1->qW1t, W2->qW2t ======================
__global__ __launch_bounds__(256) void k_quant(
    const float* __restrict__ x, const float* __restrict__ W1, const float* __restrict__ W2,
    const float* __restrict__ pmaxX, const float* __restrict__ pcm1, const float* __restrict__ pcm2,
    int8_t* __restrict__ qx, int8_t* __restrict__ qw1, int8_t* __restrict__ qw2,
    float* __restrict__ cm1, float* __restrict__ cm2, float* __restrict__ scG) {
  const int bx = blockIdx.x, tid = threadIdx.x;
  if (bx < 2048) {                     // x: reduce pmaxX then quantize 16 f32 -> int8
    __shared__ float red[4];
    float v = fmaxf(fmaxf(pmaxX[tid], pmaxX[tid + 256]),
                    fmaxf(pmaxX[tid + 512], pmaxX[tid + 768]));
    for (int s = 32; s; s >>= 1) v = fmaxf(v, __shfl_down(v, s));
    if ((tid & 63) == 0) red[tid >> 6] = v;
    __syncthreads();
    const float xmax = fmaxf(fmaxf(red[0], red[1]), fmaxf(red[2], red[3]));
    if (bx == 0 && tid == 0) scG[0] = xmax;
    const float s = 127.0f / fmaxf(xmax, EPSQ);
    size_t idx = ((size_t)bx * 256 + tid) * 16;
    union { int8_t p[16]; uint4 v; } u;
#pragma unroll
    for (int i = 0; i < 16; i += 4) {
      float4 f = *(const float4*)(x + idx + i);
      u.p[i] = quant1(f.x, s); u.p[i + 1] = quant1(f.y, s);
      u.p[i + 2] = quant1(f.z, s); u.p[i + 3] = quant1(f.w, s);
    }
    *(uint4*)(qx + idx) = u.v;
  } else if (bx < 3072) {              // W1 [1024,4096] -> qw1t [4096,1024]
    int id = (bx - 2048) * 256 + tid;
    int n = id & 4095, kc = id >> 12;
    float cmv = 0.f;
#pragma unroll
    for (int sp = 0; sp < 4; ++sp) cmv = fmaxf(cmv, pcm1[sp * 4096 + n]);
    if (kc == 0) cm1[n] = cmv;
    const float s = 127.0f / fmaxf(cmv, EPSQ);
    union { int8_t p[16]; uint4 v; } u;
#pragma unroll
    for (int j = 0; j < 16; ++j)
      u.p[j] = quant1(W1[(size_t)(kc * 16 + j) * 4096 + n], s);
    *(uint4*)(qw1 + (size_t)n * 1024 + kc * 16) = u.v;
  } else {                             // W2 [4096,1024] -> qw2t [1024,4096]
    int id = (bx - 3072) * 256 + tid;
    int n = id & 1023, kc = id >> 10;
    float cmv = 0.f;
#pragma unroll
    for (int sp = 0; sp < 16; ++sp) cmv = fmaxf(cmv, pcm2[sp * 1024 + n]);
    if (kc == 0) cm2[n] = cmv;
    const float s = 127.0f / fmaxf(cmv, EPSQ);
    union { int8_t p[16]; uint4 v; } u;
#pragma unroll
    for (int j = 0; j < 16; ++j)
      u.p[j] = quant1(W2[(size_t)(kc * 16 + j) * 1024 + n], s);
    *(uint4*)(qw2 + (size_t)n * 4096 + kc * 16) = u.v;
  }
}

// ================== GEMM: A [M,K] x Bt [N,K], 128x128, dbuf BK=64 ==================
// MODE 0: h fp16 = relu(deq+bias), per-block masked max -> pmaxH.  MODE 1: f32 out.
template <int MODE>
__global__ __launch_bounds__(256) void gemm_i8(
    const int8_t* __restrict__ A, const int8_t* __restrict__ Bt,
    const float* __restrict__ sxp, const float* __restrict__ cmax,
    const float* __restrict__ bias, const float* __restrict__ mask,
    void* __restrict__ outp, float* __restrict__ pmaxH, int M, int N, int K) {
  __shared__ __align__(16) int8_t lsA[2][128 * 64];
  __shared__ __align__(16) int8_t lsB[2][128 * 64];
  __shared__ float red[4];
  const int tid = threadIdx.x;
  const int wave = tid >> 6, lane = tid & 63;
  const int m0 = blockIdx.y * 128, n0 = blockIdx.x * 128;
  const int wm = (wave & 1) * 64, wn = (wave >> 1) * 64;

  v4i acc[4][4] = {};

  // staging: thread covers LDS row r=tid>>2, chunk c=tid&3; source chunk swizzled.
  // (r and R=g*64+r give identical (>>1)&3 since 64/2=32 ≡ 0 mod 4.)
  const int r = tid >> 2, c = tid & 3;
  const int csw = (c ^ ((r >> 1) & 3)) << 4;
  const int8_t* srcA0 = A + (size_t)(m0 + r) * K + csw;
  const int8_t* srcA1 = A + (size_t)(m0 + 64 + r) * K + csw;
  const int8_t* srcB0 = Bt + (size_t)(n0 + r) * K + csw;
  const int8_t* srcB1 = Bt + (size_t)(n0 + 64 + r) * K + csw;

  // fragment read offsets (16x16x64: row = lane&15, k-chunk = lane>>4, swizzled)
  const int fr = lane & 15, fj = lane >> 4;
  const int coff = ((fj ^ ((fr >> 1) & 3)) << 4);

  const int nsteps = K >> 6;
  // prologue: stage step 0 into buffer 0
  async16(srcA0, lsA[0] + tid * 16);
  async16(srcA1, lsA[0] + 4096 + tid * 16);
  async16(srcB0, lsB[0] + tid * 16);
  async16(srcB1, lsB[0] + 4096 + tid * 16);

  for (int kb = 0; kb < nsteps; ++kb) {
    const int cur = kb & 1;
    __syncthreads();                     // drains loads into buf cur; prev reads done
    if (kb + 1 < nsteps) {               // prefetch next step into the other buffer
      const int ko = (kb + 1) << 6;
      async16(srcA0 + ko, lsA[cur ^ 1] + tid * 16);
      async16(srcA1 + ko, lsA[cur ^ 1] + 4096 + tid * 16);
      async16(srcB0 + ko, lsB[cur ^ 1] + tid * 16);
      async16(srcB1 + ko, lsB[cur ^ 1] + 4096 + tid * 16);
    }
    v4i af[4], bf[4];
#pragma unroll
    for (int mt = 0; mt < 4; ++mt)
      af[mt] = *(const v4i*)(lsA[cur] + (wm + mt * 16 + fr) * 64 + coff);
#pragma unroll
    for (int nt = 0; nt < 4; ++nt)
      bf[nt] = *(const v4i*)(lsB[cur] + (wn + nt * 16 + fr) * 64 + coff);
#pragma unroll
    for (int mt = 0; mt < 4; ++mt)
#pragma unroll
      for (int nt = 0; nt < 4; ++nt)
        acc[mt][nt] = __builtin_amdgcn_mfma_i32_16x16x64_i8(af[mt], bf[nt], acc[mt][nt], 0, 0, 0);
  }

  const float asc = fmaxf(sxp[0], EPSQ) * (1.0f / 127.0f);
  const int cl = lane & 15;
  const int rl = (lane >> 4) * 4;

  float bsc[4], bv[4];
#pragma unroll
  for (int nt = 0; nt < 4; ++nt) {
    int col = n0 + wn + nt * 16 + cl;
    bsc[nt] = fmaxf(cmax[col], EPSQ) * (1.0f / 127.0f) * asc;
    bv[nt] = bias[col];
  }

  if (MODE == 0) {
    unsigned short* hO = (unsigned short*)outp;
    float lmax = 0.f;
#pragma unroll
    for (int mt = 0; mt < 4; ++mt)
#pragma unroll
      for (int rr = 0; rr < 4; ++rr) {
        int row = m0 + wm + mt * 16 + rl + rr;
        float mk = fabsf(mask[row]);
        unsigned short* orow = hO + (size_t)row * N + n0 + wn + cl;
#pragma unroll
        for (int nt = 0; nt < 4; ++nt) {
          float v = (float)acc[mt][nt][rr] * bsc[nt] + bv[nt];
          v = fmaxf(v, 0.f);
          orow[nt * 16] = f2h(v);
          lmax = fmaxf(lmax, v * mk);
        }
      }
    for (int s = 32; s; s >>= 1) lmax = fmaxf(lmax, __shfl_down(lmax, s));
    if (lane == 0) red[wave] = lmax;
    __syncthreads();
    if (tid == 0)
      pmaxH[blockIdx.y * gridDim.x + blockIdx.x] =
          fmaxf(fmaxf(red[0], red[1]), fmaxf(red[2], red[3]));
  } else {
    float* oO = (float*)outp;
#pragma unroll
    for (int mt = 0; mt < 4; ++mt)
#pragma unroll
      for (int rr = 0; rr < 4; ++rr) {
        int row = m0 + wm + mt * 16 + rl + rr;
        float* orow = oO + (size_t)row * N + n0 + wn + cl;
#pragma unroll
        for (int nt = 0; nt < 4; ++nt)
          orow[nt * 16] = (float)acc[mt][nt][rr] * bsc[nt] + bv[nt];
      }
  }
}

// ================== dispatch 4: quantize h (fp16) -> int8 ==========================
__global__ __launch_bounds__(256) void k_quant_h(
    const unsigned short* __restrict__ h, const float* __restrict__ pmaxH,
    float* __restrict__ scG, int8_t* __restrict__ q) {
  __shared__ float red[4];
  const int tid = threadIdx.x;
  float v = fmaxf(fmaxf(pmaxH[tid], pmaxH[tid + 256]),
                  fmaxf(pmaxH[tid + 512], pmaxH[tid + 768]));
  for (int s = 32; s; s >>= 1) v = fmaxf(v, __shfl_down(v, s));
  if ((tid & 63) == 0) red[tid >> 6] = v;
  __syncthreads();
  const float hmax = fmaxf(fmaxf(red[0], red[1]), fmaxf(red[2], red[3]));
  if (blockIdx.x == 0 && tid == 0) scG[1] = hmax;
  const float s = 127.0f / fmaxf(hmax, EPSQ);
  size_t idx = ((size_t)blockIdx.x * 256 + tid) * 16;
  union { uint4 v; unsigned short s[8]; } a, b;
  a.v = *(const uint4*)(h + idx);
  b.v = *(const uint4*)(h + idx + 8);
  union { int8_t p[16]; uint4 v; } u;
#pragma unroll
  for (int i = 0; i < 8; ++i) {
    u.p[i] = quant1(h2f(a.s[i]), s);
    u.p[i + 8] = quant1(h2f(b.s[i]), s);
  }
  *(uint4*)(q + idx) = u.v;
}

extern "C" void kernel_launch(void* const* d_in, const int* in_sizes, int n_in,
                              void* d_out, int out_size, void* d_ws, size_t ws_size,
                              hipStream_t stream) {
  const float* x  = (const float*)d_in[0];   // [8192,1024]
  const float* mk = (const float*)d_in[1];   // [8192]
  const float* W1 = (const float*)d_in[2];   // [1024,4096]
  const float* b1 = (const float*)d_in[3];   // [4096]
  const float* W2 = (const float*)d_in[4];   // [4096,1024]
  const float* b2 = (const float*)d_in[5];   // [1024]
  float* out = (float*)d_out;                // [8192,1024]

  float* scG   = (float*)d_ws;               // [8]
  float* pmaxX = scG + 8;                    // [1024]
  float* pmaxH = pmaxX + 1024;               // [1024]
  float* pcm1  = pmaxH + 1024;               // [4*4096]
  float* pcm2  = pcm1 + 16384;               // [16*1024]
  float* cm1   = pcm2 + 16384;               // [4096]
  float* cm2   = cm1 + 4096;                 // [1024]
  int8_t* qx  = (int8_t*)(cm2 + 1024);           // 8 MiB
  int8_t* qw1 = qx  + (size_t)8192 * 1024;       // 4 MiB  [4096][1024]
  int8_t* qw2 = qw1 + (size_t)4096 * 1024;       // 4 MiB  [1024][4096]
  int8_t* qh  = qw2 + (size_t)1024 * 4096;       // 32 MiB
  unsigned short* h = (unsigned short*)(qh + (size_t)8192 * 4096);  // 64 MiB fp16

  k_stats<<<1152, 256, 0, stream>>>(x, mk, W1, W2, pmaxX, pcm1, pcm2);
  k_quant<<<4096, 256, 0, stream>>>(x, W1, W2, pmaxX, pcm1, pcm2,
                                    qx, qw1, qw2, cm1, cm2, scG);
  gemm_i8<0><<<dim3(32, 64), 256, 0, stream>>>(
      qx, qw1, scG, cm1, b1, mk, (void*)h, pmaxH, 8192, 4096, 1024);
  k_quant_h<<<8192, 256, 0, stream>>>(h, pmaxH, scG, qh);
  gemm_i8<1><<<dim3(8, 64), 256, 0, stream>>>(
      qh, qw2, scG + 1, cm2, b2, mk, (void*)out, nullptr, 8192, 1024, 4096);
}

// Round 5
// 284.066 us; speedup vs baseline: 1.5094x; 1.1828x over previous
//
#include <hip/hip_runtime.h>
#include <hip/hip_fp16.h>
#include <stdint.h>

// AQT int8 MLP: M=8192, C=1024, H=4096. All I/O float32.
// Exact path: fake_quant values are q/s (integer q), so xq@wq is exact in int32 MFMA.
// 5 dispatches: stats -> quant(x,W1t,W2t) -> GEMM1(h fp16 + block hmax) -> quant_h -> GEMM2.
// GEMM: 128x128 block, 2x2 waves of 64x64, BK=64, LDS double-buffer, 1 barrier/step.

#define EPSQ 1e-6f
typedef int v4i __attribute__((ext_vector_type(4)));

__device__ __forceinline__ int8_t quant1(float x, float s) {
  return (int8_t)(int)fminf(fmaxf(rintf(x * s), -127.f), 127.f);
}
__device__ __forceinline__ void async16(const int8_t* g, int8_t* l) {
  __builtin_amdgcn_global_load_lds(
      (const __attribute__((address_space(1))) void*)g,
      (__attribute__((address_space(3))) void*)l, 16, 0, 0);
}
__device__ __forceinline__ unsigned short f2h(float f) {
  __half h = __float2half(f);
  return *(unsigned short*)&h;
}
__device__ __forceinline__ float h2f(unsigned short u) {
  __half h = *(__half*)&u;
  return __half2float(h);
}
__device__ __forceinline__ float4 max4(float4 m, float4 v) {
  m.x = fmaxf(m.x, fabsf(v.x)); m.y = fmaxf(m.y, fabsf(v.y));
  m.z = fmaxf(m.z, fabsf(v.z)); m.w = fmaxf(m.w, fabsf(v.w));
  return m;
}

// ===== dispatch 1: stats. W1: 16 rowsplits x 4 colgroups (64 blk, 64 rows each,
// 4 cols/thread float4). W2: 64 rowsplits (64 blk). x masked absmax: 1024 blk. =====
__global__ __launch_bounds__(256) void k_stats(
    const float* __restrict__ x, const float* __restrict__ mask,
    const float* __restrict__ W1, const float* __restrict__ W2,
    float* __restrict__ pmaxX, float* __restrict__ pcm1, float* __restrict__ pcm2) {
  const int bx = blockIdx.x, tid = threadIdx.x;
  if (bx < 64) {                       // W1 [1024,4096]
    const int sp = bx & 15, cg = bx >> 4;
    const int col = cg * 1024 + tid * 4;
    float4 m = {0.f, 0.f, 0.f, 0.f};
#pragma unroll 8
    for (int r = 0; r < 64; ++r)
      m = max4(m, *(const float4*)(W1 + (size_t)(sp * 64 + r) * 4096 + col));
    *(float4*)(pcm1 + sp * 4096 + col) = m;
  } else if (bx < 128) {               // W2 [4096,1024]
    const int sp = bx - 64;
    const int col = tid * 4;
    float4 m = {0.f, 0.f, 0.f, 0.f};
#pragma unroll 8
    for (int r = 0; r < 64; ++r)
      m = max4(m, *(const float4*)(W2 + (size_t)(sp * 64 + r) * 1024 + col));
    *(float4*)(pcm2 + sp * 1024 + col) = m;
  } else {                             // masked absmax of x -> per-block partial
    __shared__ float red[4];
    const int b = bx - 128;            // 1024 blocks
    float lmax = 0.f;
    for (int c = b * 256 + tid; c < 1048576; c += 262144) {
      size_t idx = (size_t)c * 8;
      float mk = fabsf(mask[idx >> 10]);
      float4 m4 = {0.f, 0.f, 0.f, 0.f};
      m4 = max4(m4, *(const float4*)(x + idx));
      m4 = max4(m4, *(const float4*)(x + idx + 4));
      lmax = fmaxf(lmax, fmaxf(fmaxf(m4.x, m4.y), fmaxf(m4.z, m4.w)) * mk);
    }
    for (int s = 32; s; s >>= 1) lmax = fmaxf(lmax, __shfl_down(lmax, s));
    if ((tid & 63) == 0) red[tid >> 6] = lmax;
    __syncthreads();
    if (tid == 0)
      pmaxX[b] = fmaxf(fmaxf(red[0], red[1]), fmaxf(red[2], red[3]));
  }
}

// ===== dispatch 2: quantize x (2048 blk), W1->qW1t (256 blk), W2->qW2t (256 blk) ====
__global__ __launch_bounds__(256) void k_quant(
    const float* __restrict__ x, const float* __restrict__ W1, const float* __restrict__ W2,
    const float* __restrict__ pmaxX, const float* __restrict__ pcm1, const float* __restrict__ pcm2,
    int8_t* __restrict__ qx, int8_t* __restrict__ qw1, int8_t* __restrict__ qw2,
    float* __restrict__ cm1, float* __restrict__ cm2, float* __restrict__ scG) {
  const int bx = blockIdx.x, tid = threadIdx.x;
  if (bx < 2048) {                     // x: reduce pmaxX then quantize 16 f32 -> int8
    __shared__ float red[4];
    float v = fmaxf(fmaxf(pmaxX[tid], pmaxX[tid + 256]),
                    fmaxf(pmaxX[tid + 512], pmaxX[tid + 768]));
    for (int s = 32; s; s >>= 1) v = fmaxf(v, __shfl_down(v, s));
    if ((tid & 63) == 0) red[tid >> 6] = v;
    __syncthreads();
    const float xmax = fmaxf(fmaxf(red[0], red[1]), fmaxf(red[2], red[3]));
    if (bx == 0 && tid == 0) scG[0] = xmax;
    const float s = 127.0f / fmaxf(xmax, EPSQ);
    size_t idx = ((size_t)bx * 256 + tid) * 16;
    union { int8_t p[16]; uint4 v; } u;
#pragma unroll
    for (int i = 0; i < 16; i += 4) {
      float4 f = *(const float4*)(x + idx + i);
      u.p[i] = quant1(f.x, s); u.p[i + 1] = quant1(f.y, s);
      u.p[i + 2] = quant1(f.z, s); u.p[i + 3] = quant1(f.w, s);
    }
    *(uint4*)(qx + idx) = u.v;
  } else if (bx < 2304) {              // W1 [1024,4096] -> qw1t [4096,1024], 4 cols/thr
    int id = (bx - 2048) * 256 + tid;  // 65536 tasks
    int n4 = id & 1023, kc = id >> 10; // col=n4*4, kc in 0..63
    const int col = n4 * 4;
    float4 cm = {0.f, 0.f, 0.f, 0.f};
#pragma unroll
    for (int sp = 0; sp < 16; ++sp) {
      float4 p = *(const float4*)(pcm1 + sp * 4096 + col);
      cm.x = fmaxf(cm.x, p.x); cm.y = fmaxf(cm.y, p.y);
      cm.z = fmaxf(cm.z, p.z); cm.w = fmaxf(cm.w, p.w);
    }
    if (kc == 0) *(float4*)(cm1 + col) = cm;
    const float s0 = 127.0f / fmaxf(cm.x, EPSQ), s1 = 127.0f / fmaxf(cm.y, EPSQ);
    const float s2 = 127.0f / fmaxf(cm.z, EPSQ), s3 = 127.0f / fmaxf(cm.w, EPSQ);
    union { int8_t p[16]; uint4 v; } u0, u1, u2, u3;
#pragma unroll
    for (int j = 0; j < 16; ++j) {
      float4 f = *(const float4*)(W1 + (size_t)(kc * 16 + j) * 4096 + col);
      u0.p[j] = quant1(f.x, s0); u1.p[j] = quant1(f.y, s1);
      u2.p[j] = quant1(f.z, s2); u3.p[j] = quant1(f.w, s3);
    }
    int8_t* base = qw1 + (size_t)col * 1024 + kc * 16;
    *(uint4*)(base) = u0.v;          *(uint4*)(base + 1024) = u1.v;
    *(uint4*)(base + 2048) = u2.v;   *(uint4*)(base + 3072) = u3.v;
  } else {                             // W2 [4096,1024] -> qw2t [1024,4096], 4 cols/thr
    int id = (bx - 2304) * 256 + tid;  // 65536 tasks
    int n4 = id & 255, kc = id >> 8;   // col=n4*4, kc in 0..255
    const int col = n4 * 4;
    float4 cm = {0.f, 0.f, 0.f, 0.f};
#pragma unroll
    for (int sp = 0; sp < 64; ++sp) {
      float4 p = *(const float4*)(pcm2 + sp * 1024 + col);
      cm.x = fmaxf(cm.x, p.x); cm.y = fmaxf(cm.y, p.y);
      cm.z = fmaxf(cm.z, p.z); cm.w = fmaxf(cm.w, p.w);
    }
    if (kc == 0) *(float4*)(cm2 + col) = cm;
    const float s0 = 127.0f / fmaxf(cm.x, EPSQ), s1 = 127.0f / fmaxf(cm.y, EPSQ);
    const float s2 = 127.0f / fmaxf(cm.z, EPSQ), s3 = 127.0f / fmaxf(cm.w, EPSQ);
    union { int8_t p[16]; uint4 v; } u0, u1, u2, u3;
#pragma unroll
    for (int j = 0; j < 16; ++j) {
      float4 f = *(const float4*)(W2 + (size_t)(kc * 16 + j) * 1024 + col);
      u0.p[j] = quant1(f.x, s0); u1.p[j] = quant1(f.y, s1);
      u2.p[j] = quant1(f.z, s2); u3.p[j] = quant1(f.w, s3);
    }
    int8_t* base = qw2 + (size_t)col * 4096 + kc * 16;
    *(uint4*)(base) = u0.v;          *(uint4*)(base + 4096) = u1.v;
    *(uint4*)(base + 8192) = u2.v;   *(uint4*)(base + 12288) = u3.v;
  }
}

// ================== GEMM: A [M,K] x Bt [N,K], 128x128, dbuf BK=64 ==================
// MODE 0: h fp16 = relu(deq+bias), per-block masked max -> pmaxH.  MODE 1: f32 out.
template <int MODE>
__global__ __launch_bounds__(256) void gemm_i8(
    const int8_t* __restrict__ A, const int8_t* __restrict__ Bt,
    const float* __restrict__ sxp, const float* __restrict__ cmax,
    const float* __restrict__ bias, const float* __restrict__ mask,
    void* __restrict__ outp, float* __restrict__ pmaxH, int M, int N, int K) {
  __shared__ __align__(16) int8_t lsA[2][128 * 64];
  __shared__ __align__(16) int8_t lsB[2][128 * 64];
  __shared__ float red[4];
  const int tid = threadIdx.x;
  const int wave = tid >> 6, lane = tid & 63;
  const int m0 = blockIdx.y * 128, n0 = blockIdx.x * 128;
  const int wm = (wave & 1) * 64, wn = (wave >> 1) * 64;

  v4i acc[4][4] = {};

  const int r = tid >> 2, c = tid & 3;
  const int csw = (c ^ ((r >> 1) & 3)) << 4;
  const int8_t* srcA0 = A + (size_t)(m0 + r) * K + csw;
  const int8_t* srcA1 = A + (size_t)(m0 + 64 + r) * K + csw;
  const int8_t* srcB0 = Bt + (size_t)(n0 + r) * K + csw;
  const int8_t* srcB1 = Bt + (size_t)(n0 + 64 + r) * K + csw;

  const int fr = lane & 15, fj = lane >> 4;
  const int coff = ((fj ^ ((fr >> 1) & 3)) << 4);

  const int nsteps = K >> 6;
  async16(srcA0, lsA[0] + tid * 16);
  async16(srcA1, lsA[0] + 4096 + tid * 16);
  async16(srcB0, lsB[0] + tid * 16);
  async16(srcB1, lsB[0] + 4096 + tid * 16);

  for (int kb = 0; kb < nsteps; ++kb) {
    const int cur = kb & 1;
    __syncthreads();
    if (kb + 1 < nsteps) {
      const int ko = (kb + 1) << 6;
      async16(srcA0 + ko, lsA[cur ^ 1] + tid * 16);
      async16(srcA1 + ko, lsA[cur ^ 1] + 4096 + tid * 16);
      async16(srcB0 + ko, lsB[cur ^ 1] + tid * 16);
      async16(srcB1 + ko, lsB[cur ^ 1] + 4096 + tid * 16);
    }
    v4i af[4], bf[4];
#pragma unroll
    for (int mt = 0; mt < 4; ++mt)
      af[mt] = *(const v4i*)(lsA[cur] + (wm + mt * 16 + fr) * 64 + coff);
#pragma unroll
    for (int nt = 0; nt < 4; ++nt)
      bf[nt] = *(const v4i*)(lsB[cur] + (wn + nt * 16 + fr) * 64 + coff);
#pragma unroll
    for (int mt = 0; mt < 4; ++mt)
#pragma unroll
      for (int nt = 0; nt < 4; ++nt)
        acc[mt][nt] = __builtin_amdgcn_mfma_i32_16x16x64_i8(af[mt], bf[nt], acc[mt][nt], 0, 0, 0);
  }

  const float asc = fmaxf(sxp[0], EPSQ) * (1.0f / 127.0f);
  const int cl = lane & 15;
  const int rl = (lane >> 4) * 4;

  float bsc[4], bv[4];
#pragma unroll
  for (int nt = 0; nt < 4; ++nt) {
    int col = n0 + wn + nt * 16 + cl;
    bsc[nt] = fmaxf(cmax[col], EPSQ) * (1.0f / 127.0f) * asc;
    bv[nt] = bias[col];
  }

  if (MODE == 0) {
    unsigned short* hO = (unsigned short*)outp;
    float lmax = 0.f;
#pragma unroll
    for (int mt = 0; mt < 4; ++mt)
#pragma unroll
      for (int rr = 0; rr < 4; ++rr) {
        int row = m0 + wm + mt * 16 + rl + rr;
        float mk = fabsf(mask[row]);
        unsigned short* orow = hO + (size_t)row * N + n0 + wn + cl;
#pragma unroll
        for (int nt = 0; nt < 4; ++nt) {
          float v = (float)acc[mt][nt][rr] * bsc[nt] + bv[nt];
          v = fmaxf(v, 0.f);
          orow[nt * 16] = f2h(v);
          lmax = fmaxf(lmax, v * mk);
        }
      }
    for (int s = 32; s; s >>= 1) lmax = fmaxf(lmax, __shfl_down(lmax, s));
    if (lane == 0) red[wave] = lmax;
    __syncthreads();
    if (tid == 0)
      pmaxH[blockIdx.y * gridDim.x + blockIdx.x] =
          fmaxf(fmaxf(red[0], red[1]), fmaxf(red[2], red[3]));
  } else {
    float* oO = (float*)outp;
#pragma unroll
    for (int mt = 0; mt < 4; ++mt)
#pragma unroll
      for (int rr = 0; rr < 4; ++rr) {
        int row = m0 + wm + mt * 16 + rl + rr;
        float* orow = oO + (size_t)row * N + n0 + wn + cl;
#pragma unroll
        for (int nt = 0; nt < 4; ++nt)
          orow[nt * 16] = (float)acc[mt][nt][rr] * bsc[nt] + bv[nt];
      }
  }
}

// ===== dispatch 4: quantize h (fp16) -> int8; reduce ALL 2048 pmaxH partials =======
__global__ __launch_bounds__(256) void k_quant_h(
    const unsigned short* __restrict__ h, const float* __restrict__ pmaxH,
    float* __restrict__ scG, int8_t* __restrict__ q) {
  __shared__ float red[4];
  const int tid = threadIdx.x;
  float v = 0.f;
#pragma unroll
  for (int j = 0; j < 8; ++j) v = fmaxf(v, pmaxH[tid + 256 * j]);
  for (int s = 32; s; s >>= 1) v = fmaxf(v, __shfl_down(v, s));
  if ((tid & 63) == 0) red[tid >> 6] = v;
  __syncthreads();
  const float hmax = fmaxf(fmaxf(red[0], red[1]), fmaxf(red[2], red[3]));
  if (blockIdx.x == 0 && tid == 0) scG[1] = hmax;
  const float s = 127.0f / fmaxf(hmax, EPSQ);
  size_t idx = ((size_t)blockIdx.x * 256 + tid) * 16;
  union { uint4 v; unsigned short s[8]; } a, b;
  a.v = *(const uint4*)(h + idx);
  b.v = *(const uint4*)(h + idx + 8);
  union { int8_t p[16]; uint4 v; } u;
#pragma unroll
  for (int i = 0; i < 8; ++i) {
    u.p[i] = quant1(h2f(a.s[i]), s);
    u.p[i + 8] = quant1(h2f(b.s[i]), s);
  }
  *(uint4*)(q + idx) = u.v;
}

extern "C" void kernel_launch(void* const* d_in, const int* in_sizes, int n_in,
                              void* d_out, int out_size, void* d_ws, size_t ws_size,
                              hipStream_t stream) {
  const float* x  = (const float*)d_in[0];   // [8192,1024]
  const float* mk = (const float*)d_in[1];   // [8192]
  const float* W1 = (const float*)d_in[2];   // [1024,4096]
  const float* b1 = (const float*)d_in[3];   // [4096]
  const float* W2 = (const float*)d_in[4];   // [4096,1024]
  const float* b2 = (const float*)d_in[5];   // [1024]
  float* out = (float*)d_out;                // [8192,1024]

  float* scG   = (float*)d_ws;               // [8]
  float* pmaxX = scG + 8;                    // [1024]
  float* pmaxH = pmaxX + 1024;               // [2048]
  float* pcm1  = pmaxH + 2048;               // [16*4096]
  float* pcm2  = pcm1 + 65536;               // [64*1024]
  float* cm1   = pcm2 + 65536;               // [4096]
  float* cm2   = cm1 + 4096;                 // [1024]
  int8_t* qx  = (int8_t*)(cm2 + 1024);           // 8 MiB
  int8_t* qw1 = qx  + (size_t)8192 * 1024;       // 4 MiB  [4096][1024]
  int8_t* qw2 = qw1 + (size_t)4096 * 1024;       // 4 MiB  [1024][4096]
  int8_t* qh  = qw2 + (size_t)1024 * 4096;       // 32 MiB
  unsigned short* h = (unsigned short*)(qh + (size_t)8192 * 4096);  // 64 MiB fp16

  k_stats<<<1152, 256, 0, stream>>>(x, mk, W1, W2, pmaxX, pcm1, pcm2);
  k_quant<<<2560, 256, 0, stream>>>(x, W1, W2, pmaxX, pcm1, pcm2,
                                    qx, qw1, qw2, cm1, cm2, scG);
  gemm_i8<0><<<dim3(32, 64), 256, 0, stream>>>(
      qx, qw1, scG, cm1, b1, mk, (void*)h, pmaxH, 8192, 4096, 1024);
  k_quant_h<<<8192, 256, 0, stream>>>(h, pmaxH, scG, qh);
  gemm_i8<1><<<dim3(8, 64), 256, 0, stream>>>(
      qh, qw2, scG + 1, cm2, b2, mk, (void*)out, nullptr, 8192, 1024, 4096);
}